// Round 18
// baseline (304.048 us; speedup 1.0000x reference)
//
#include <hip/hip_runtime.h>
#include <math.h>

#define MAXT 100000.0f
#define M_OUT 1024
#define BATCH 64
#define PITCH 1040      // 1025 real + pads covering depth-4 offset overrun (ints <= 1039)
#define WALL() __builtin_amdgcn_sched_barrier(0)

// ws layout (floats/ints):
//   sx    [64][PITCH]            @ 0
//   soff  [64][PITCH]            @ 64*PITCH
//   segw  [64][4][16][256]       @ 2*64*PITCH
//   segwt [64][4][16][256]       @ 2*64*PITCH + 64*4*16*256
#define SEGBASE (2 * BATCH * PITCH)
#define SEGSZ   (BATCH * 4 * 16 * 256)

// ---------------------------------------------------------------------------
// Kernel 1 (R13, verified): stable rank via u32 keys, split-j. Also inits
// out[] to MAXT (pass2 atomicMins into it) and rewrites sx/soff pads.
// ---------------------------------------------------------------------------
__global__ __launch_bounds__(512) void rank_kernel(const float* __restrict__ X,
                                                   float* __restrict__ sx,
                                                   int* __restrict__ soff,
                                                   float* __restrict__ out) {
    const int b   = blockIdx.y;
    const int tid = threadIdx.x;            // 0..511
    const int t   = tid & 255;              // key slot within block
    const int i   = blockIdx.x * 256 + t;   // key index 0..1279
    __shared__ __align__(16) unsigned keys[1032];
    __shared__ int part[256];

    const float myx = (i < 1024) ? X[b * 1024 + i] : 1.0f;

#pragma unroll
    for (int c = 0; c < 2; ++c) {
        const int ii = c * 512 + tid;
        const float v = X[b * 1024 + ii];
        keys[ii] = (((__float_as_uint(v) - 0x3F800000u) >> 2) << 11) | (unsigned)ii;
    }
    if (tid == 0) keys[1024] = 1024u;                       // bias: mantissa 0 | idx 1024
    else if (tid < 8) keys[1024 + tid] = 0xFFFFFFFFu;       // pads: > all real keys
    if (blockIdx.x < 4 && tid < 256)
        out[b * M_OUT + blockIdx.x * 256 + tid] = MAXT;     // init for atomicMin
    __syncthreads();

    const unsigned ki = keys[(i < 1032) ? i : 1031];        // guard OOB LDS read
    const int j0 = (tid < 256) ? 0 : 516;
    int r0 = 0, r1 = 0;
#pragma unroll 8
    for (int j = j0; j < j0 + 512; j += 8) {
        const uint4 a = *(const uint4*)&keys[j];
        const uint4 c = *(const uint4*)&keys[j + 4];
        r0 += (int)(a.x < ki) + (int)(a.y < ki) + (int)(a.z < ki) + (int)(a.w < ki);
        r1 += (int)(c.x < ki) + (int)(c.y < ki) + (int)(c.z < ki) + (int)(c.w < ki);
    }
    {   // last quad of the 516-wide half-range
        const uint4 a = *(const uint4*)&keys[j0 + 512];
        r0 += (int)(a.x < ki) + (int)(a.y < ki) + (int)(a.z < ki) + (int)(a.w < ki);
    }
    if (tid >= 256) part[t] = r0 + r1;
    __syncthreads();

    if (tid < 256) {
        if (i <= 1024) {
            const int rank = r0 + r1 + part[t];
            sx[b * PITCH + rank]   = myx;
            soff[b * PITCH + rank] = i * 4096;              // byte offset into W
        } else if (i < PITCH) {
            sx[b * PITCH + i] = MAXT; soff[b * PITCH + i] = 0;  // sentinels
        }
    }
}

// ---------------------------------------------------------------------------
// Pass 1: segment sums. Grid (4 mb, 64 b, 4 sg) x 256 thr. Wave = one
// 64-row segment x 256 cols (4/lane). 256-thr blocks lift the VGPR cap
// (R8/R17 ledger: cap scales with block size; 1024thr pinned us to 64 and
// spilled R13/R15/R16) -> depth-4 circular float4 pipeline (64 VGPR bufs,
// 12 loads in flight) finally fits. No LDS, no barriers; off/xs read
// wave-uniform from global -> s_load (proven R7).
// ---------------------------------------------------------------------------
__global__ __launch_bounds__(256, 4) void snn_pass1(const float* __restrict__ W,
                                                    const float* __restrict__ sx,
                                                    const int* __restrict__ soff,
                                                    float* __restrict__ ws) {
    const int mb   = blockIdx.x;
    const int b    = blockIdx.y;
    const int wv   = threadIdx.x >> 6;
    const int lane = threadIdx.x & 63;
    const int seg  = blockIdx.z * 4 + wv;          // 0..15

    const char* Wq = (const char*)W + (size_t)(mb * 256 + lane * 4) * 4;
    const int4*  off4 = (const int4*)(soff + b * PITCH);
    const float* xs   = sx + b * PITCH;
    const int k0 = seg * 64;
    const int base = k0 >> 2;

#define LOADB(dst, o)                                                          \
    do {                                                                       \
        dst[0] = *(const float4*)(Wq + (o).x);                                 \
        dst[1] = *(const float4*)(Wq + (o).y);                                 \
        dst[2] = *(const float4*)(Wq + (o).z);                                 \
        dst[3] = *(const float4*)(Wq + (o).w);                                 \
    } while (0)

    float cw0 = 0, cw1 = 0, cw2 = 0, cw3 = 0;
    float ct0 = 0, ct1 = 0, ct2 = 0, ct3 = 0;

#define ACC(wvv, xx)                                                           \
    do {                                                                       \
        cw0 = __fadd_rn(cw0, (wvv).x); ct0 = __builtin_fmaf((wvv).x, (xx), ct0); \
        cw1 = __fadd_rn(cw1, (wvv).y); ct1 = __builtin_fmaf((wvv).y, (xx), ct1); \
        cw2 = __fadd_rn(cw2, (wvv).z); ct2 = __builtin_fmaf((wvv).z, (xx), ct2); \
        cw3 = __fadd_rn(cw3, (wvv).w); ct3 = __builtin_fmaf((wvv).w, (xx), ct3); \
    } while (0)

    {
        float4 buf[4][4];
#pragma unroll
        for (int p = 0; p < 4; ++p) { const int4 o = off4[base + p]; LOADB(buf[p], o); }
        WALL();
#pragma unroll
        for (int it = 0; it < 16; ++it) {
            const int k = k0 + it * 4;
            ACC(buf[it & 3][0], xs[k]);
            ACC(buf[it & 3][1], xs[k + 1]);
            ACC(buf[it & 3][2], xs[k + 2]);
            ACC(buf[it & 3][3], xs[k + 3]);
            WALL();
            const int4 o = off4[base + it + 4];    // pads safe (ints <= 1039)
            LOADB(buf[it & 3], o);
            WALL();
        }
    }

    const int sidx = ((b * 4 + mb) * 16 + seg) * 256 + lane * 4;
    *(float4*)&ws[SEGBASE + sidx]         = make_float4(cw0, cw1, cw2, cw3);
    *(float4*)&ws[SEGBASE + SEGSZ + sidx] = make_float4(ct0, ct1, ct2, ct3);
}

// ---------------------------------------------------------------------------
// Pass 2: gated scan. Same geometry as pass 1. Wave loads its exclusive
// prefix from ws (<=15 coalesced float4 pairs, ascending s to keep the fadd
// order compensable), then scans its segment with the depth-4 pipeline.
// First-valid lock (windows ordered in k), cross-multiplied gates, one IEEE
// div; block-local min over 4 segments in LDS, then one atomicMin (uint
// bits; all candidates > 0 so uint order == float order) per col per block.
// ---------------------------------------------------------------------------
__global__ __launch_bounds__(256, 4) void snn_pass2(const float* __restrict__ W,
                                                    const float* __restrict__ sx,
                                                    const int* __restrict__ soff,
                                                    const float* __restrict__ ws,
                                                    float* __restrict__ out) {
    const int mb   = blockIdx.x;
    const int b    = blockIdx.y;
    const int wv   = threadIdx.x >> 6;
    const int lane = threadIdx.x & 63;
    const int seg  = blockIdx.z * 4 + wv;          // 0..15

    __shared__ __align__(16) float best[4][256];

    const char* Wq = (const char*)W + (size_t)(mb * 256 + lane * 4) * 4;
    const int4*  off4 = (const int4*)(soff + b * PITCH);
    const float* xs   = sx + b * PITCH;
    const int k0 = seg * 64;
    const int base = k0 >> 2;

    // ---- exclusive prefix over segments (ascending s) ----
    float cw0 = 0, cw1 = 0, cw2 = 0, cw3 = 0;
    float ct0 = 0, ct1 = 0, ct2 = 0, ct3 = 0;
    const int pidx = (b * 4 + mb) * 16 * 256 + lane * 4;
    for (int s = 0; s < seg; ++s) {
        const float4 a = *(const float4*)&ws[SEGBASE + pidx + s * 256];
        const float4 t = *(const float4*)&ws[SEGBASE + SEGSZ + pidx + s * 256];
        cw0 = __fadd_rn(cw0, a.x); cw1 = __fadd_rn(cw1, a.y);
        cw2 = __fadd_rn(cw2, a.z); cw3 = __fadd_rn(cw3, a.w);
        ct0 = __fadd_rn(ct0, t.x); ct1 = __fadd_rn(ct1, t.y);
        ct2 = __fadd_rn(ct2, t.z); ct3 = __fadd_rn(ct3, t.w);
    }

    float bn0 = 0, bn1 = 0, bn2 = 0, bn3 = 0;
    float bd0 = -1.0f, bd1 = -1.0f, bd2 = -1.0f, bd3 = -1.0f;

#define GATE(cwv, ctv, bnv, bdv, wvv, xx, xxn)                                 \
    do {                                                                       \
        cwv = __fadd_rn(cwv, (wvv));                                           \
        ctv = __builtin_fmaf((wvv), (xx), ctv);                                \
        const float dn = __fadd_rn(cwv, -1.0f);                                \
        const bool v = (ctv >= __fmul_rn((xx), dn))                            \
                     & (ctv <= __fmul_rn((xxn), dn));                          \
        const bool u = v & (bdv < 0.0f);                                       \
        bnv = u ? ctv : bnv;                                                   \
        bdv = u ? dn  : bdv;                                                   \
    } while (0)

#define GATE4(wvv, xx, xxn)                                                    \
    do {                                                                       \
        GATE(cw0, ct0, bn0, bd0, (wvv).x, (xx), (xxn));                        \
        GATE(cw1, ct1, bn1, bd1, (wvv).y, (xx), (xxn));                        \
        GATE(cw2, ct2, bn2, bd2, (wvv).z, (xx), (xxn));                        \
        GATE(cw3, ct3, bn3, bd3, (wvv).w, (xx), (xxn));                        \
    } while (0)

    {
        float4 buf[4][4];
#pragma unroll
        for (int p = 0; p < 4; ++p) { const int4 o = off4[base + p]; LOADB(buf[p], o); }
        WALL();
#pragma unroll
        for (int it = 0; it < 16; ++it) {
            const int k = k0 + it * 4;
            const float xa = xs[k],     xb = xs[k + 1];
            const float xc = xs[k + 2], xd = xs[k + 3], xe = xs[k + 4];
            GATE4(buf[it & 3][0], xa, xb);
            GATE4(buf[it & 3][1], xb, xc);
            GATE4(buf[it & 3][2], xc, xd);
            GATE4(buf[it & 3][3], xd, xe);
            WALL();
            const int4 o = off4[base + it + 4];
            LOADB(buf[it & 3], o);
            WALL();
        }
        if (seg == 15) {
            // epilogue row 1024: buf[0] reloaded at it=12 from off4[256] (.x = off[1024])
            GATE4(buf[0][0], xs[1024], xs[1025]);           // xs[1025] = MAXT pad
        }
    }

    const float c0 = (bd0 > 0.0f) ? bn0 / bd0 : MAXT;       // exact IEEE div
    const float c1 = (bd1 > 0.0f) ? bn1 / bd1 : MAXT;
    const float c2 = (bd2 > 0.0f) ? bn2 / bd2 : MAXT;
    const float c3 = (bd3 > 0.0f) ? bn3 / bd3 : MAXT;
    *(float4*)&best[wv][lane * 4] = make_float4(c0, c1, c2, c3);
    __syncthreads();

    if (threadIdx.x < 256) {
        const int t = threadIdx.x;
        float r = fminf(fminf(best[0][t], best[1][t]), fminf(best[2][t], best[3][t]));
        atomicMin((unsigned*)(out + b * M_OUT + mb * 256 + t), __float_as_uint(r));
    }
}

extern "C" void kernel_launch(void* const* d_in, const int* in_sizes, int n_in,
                              void* d_out, int out_size, void* d_ws, size_t ws_size,
                              hipStream_t stream) {
    const float* X = (const float*)d_in[0];   // [64, 1024]
    const float* W = (const float*)d_in[1];   // [1025, 1024]
    float* out = (float*)d_out;               // [64, 1024]

    float* wsf  = (float*)d_ws;
    float* sx   = wsf;                                     // [64][PITCH]
    int*   soff = (int*)(wsf + BATCH * PITCH);             // [64][PITCH]

    dim3 g1(5, BATCH);
    rank_kernel<<<g1, 512, 0, stream>>>(X, sx, soff, out);

    dim3 gp(4, BATCH, 4);
    snn_pass1<<<gp, 256, 0, stream>>>(W, sx, soff, wsf);
    snn_pass2<<<gp, 256, 0, stream>>>(W, sx, soff, wsf, out);
}

// Round 19
// 134.544 us; speedup vs baseline: 2.2598x; 2.2598x over previous
//
#include <hip/hip_runtime.h>
#include <math.h>

#define MAXT 100000.0f
#define M_OUT 1024
#define BATCH 64
#define PITCH 1040      // 1025 real + pads covering depth-4 offset overrun (ints <= 1039)
#define WALL() __builtin_amdgcn_sched_barrier(0)

// ws layout (floats/ints):
//   sx    [64][PITCH]            @ 0
//   soff  [64][PITCH]            @ 64*PITCH
//   segw  [64][4][16][256]       @ 2*64*PITCH
//   segwt [64][4][16][256]       @ 2*64*PITCH + 64*4*16*256
#define SEGBASE (2 * BATCH * PITCH)
#define SEGSZ   (BATCH * 4 * 16 * 256)

// ---------------------------------------------------------------------------
// Kernel 1 (R13, verified): stable rank via u32 keys, split-j. Also inits
// out[] to MAXT (pass2 atomicMins into it) and rewrites sx/soff pads.
// ---------------------------------------------------------------------------
__global__ __launch_bounds__(512) void rank_kernel(const float* __restrict__ X,
                                                   float* __restrict__ sx,
                                                   int* __restrict__ soff,
                                                   float* __restrict__ out) {
    const int b   = blockIdx.y;
    const int tid = threadIdx.x;            // 0..511
    const int t   = tid & 255;              // key slot within block
    const int i   = blockIdx.x * 256 + t;   // key index 0..1279
    __shared__ __align__(16) unsigned keys[1032];
    __shared__ int part[256];

    const float myx = (i < 1024) ? X[b * 1024 + i] : 1.0f;

#pragma unroll
    for (int c = 0; c < 2; ++c) {
        const int ii = c * 512 + tid;
        const float v = X[b * 1024 + ii];
        keys[ii] = (((__float_as_uint(v) - 0x3F800000u) >> 2) << 11) | (unsigned)ii;
    }
    if (tid == 0) keys[1024] = 1024u;                       // bias: mantissa 0 | idx 1024
    else if (tid < 8) keys[1024 + tid] = 0xFFFFFFFFu;       // pads: > all real keys
    if (blockIdx.x < 4 && tid < 256)
        out[b * M_OUT + blockIdx.x * 256 + tid] = MAXT;     // init for atomicMin
    __syncthreads();

    const unsigned ki = keys[(i < 1032) ? i : 1031];        // guard OOB LDS read
    const int j0 = (tid < 256) ? 0 : 516;
    int r0 = 0, r1 = 0;
#pragma unroll 8
    for (int j = j0; j < j0 + 512; j += 8) {
        const uint4 a = *(const uint4*)&keys[j];
        const uint4 c = *(const uint4*)&keys[j + 4];
        r0 += (int)(a.x < ki) + (int)(a.y < ki) + (int)(a.z < ki) + (int)(a.w < ki);
        r1 += (int)(c.x < ki) + (int)(c.y < ki) + (int)(c.z < ki) + (int)(c.w < ki);
    }
    {   // last quad of the 516-wide half-range
        const uint4 a = *(const uint4*)&keys[j0 + 512];
        r0 += (int)(a.x < ki) + (int)(a.y < ki) + (int)(a.z < ki) + (int)(a.w < ki);
    }
    if (tid >= 256) part[t] = r0 + r1;
    __syncthreads();

    if (tid < 256) {
        if (i <= 1024) {
            const int rank = r0 + r1 + part[t];
            sx[b * PITCH + rank]   = myx;
            soff[b * PITCH + rank] = i * 4096;              // byte offset into W
        } else if (i < PITCH) {
            sx[b * PITCH + i] = MAXT; soff[b * PITCH + i] = 0;  // sentinels
        }
    }
}

// ---------------------------------------------------------------------------
// Pass 1: segment sums. Grid (4 mb, 64 b, 4 sg) x 256 thr. Wave = one
// 64-row segment x 256 cols (4/lane), depth-4 circular float4 pipeline
// (12 loads in flight). __launch_bounds__(256, 1): the ledger shows the
// SECOND launch_bounds arg (min waves/EU) is what throttles the allocator
// to 64 VGPR (R8: (256,1)->88 VGPR; R18: (256,4)->64 + spill). At (256,1)
// the cap is 512; occupancy is grid-limited to 4 waves/SIMD regardless
// (1024 blocks x 4 waves on 256 CUs), so nothing is lost.
// ---------------------------------------------------------------------------
__global__ __launch_bounds__(256, 1) void snn_pass1(const float* __restrict__ W,
                                                    const float* __restrict__ sx,
                                                    const int* __restrict__ soff,
                                                    float* __restrict__ ws) {
    const int mb   = blockIdx.x;
    const int b    = blockIdx.y;
    const int wv   = threadIdx.x >> 6;
    const int lane = threadIdx.x & 63;
    const int seg  = blockIdx.z * 4 + wv;          // 0..15

    const char* Wq = (const char*)W + (size_t)(mb * 256 + lane * 4) * 4;
    const int4*  off4 = (const int4*)(soff + b * PITCH);
    const float* xs   = sx + b * PITCH;
    const int k0 = seg * 64;
    const int base = k0 >> 2;

#define LOADB(dst, o)                                                          \
    do {                                                                       \
        dst[0] = *(const float4*)(Wq + (o).x);                                 \
        dst[1] = *(const float4*)(Wq + (o).y);                                 \
        dst[2] = *(const float4*)(Wq + (o).z);                                 \
        dst[3] = *(const float4*)(Wq + (o).w);                                 \
    } while (0)

    float cw0 = 0, cw1 = 0, cw2 = 0, cw3 = 0;
    float ct0 = 0, ct1 = 0, ct2 = 0, ct3 = 0;

#define ACC(wvv, xx)                                                           \
    do {                                                                       \
        cw0 = __fadd_rn(cw0, (wvv).x); ct0 = __builtin_fmaf((wvv).x, (xx), ct0); \
        cw1 = __fadd_rn(cw1, (wvv).y); ct1 = __builtin_fmaf((wvv).y, (xx), ct1); \
        cw2 = __fadd_rn(cw2, (wvv).z); ct2 = __builtin_fmaf((wvv).z, (xx), ct2); \
        cw3 = __fadd_rn(cw3, (wvv).w); ct3 = __builtin_fmaf((wvv).w, (xx), ct3); \
    } while (0)

    {
        float4 buf[4][4];
#pragma unroll
        for (int p = 0; p < 4; ++p) { const int4 o = off4[base + p]; LOADB(buf[p], o); }
        WALL();
#pragma unroll
        for (int it = 0; it < 16; ++it) {
            const int k = k0 + it * 4;
            ACC(buf[it & 3][0], xs[k]);
            ACC(buf[it & 3][1], xs[k + 1]);
            ACC(buf[it & 3][2], xs[k + 2]);
            ACC(buf[it & 3][3], xs[k + 3]);
            WALL();
            const int4 o = off4[base + it + 4];    // pads safe (ints <= 1039)
            LOADB(buf[it & 3], o);
            WALL();
        }
    }

    const int sidx = ((b * 4 + mb) * 16 + seg) * 256 + lane * 4;
    *(float4*)&ws[SEGBASE + sidx]         = make_float4(cw0, cw1, cw2, cw3);
    *(float4*)&ws[SEGBASE + SEGSZ + sidx] = make_float4(ct0, ct1, ct2, ct3);
}

// ---------------------------------------------------------------------------
// Pass 2: gated scan. Same geometry; wave loads its exclusive prefix from
// ws (ascending s), then scans its segment with the depth-4 pipeline.
// First-valid lock, cross-multiplied gates, one IEEE div; block-local min
// over 4 segments in LDS, one atomicMin (uint bits; candidates > 0) per col.
// ---------------------------------------------------------------------------
__global__ __launch_bounds__(256, 1) void snn_pass2(const float* __restrict__ W,
                                                    const float* __restrict__ sx,
                                                    const int* __restrict__ soff,
                                                    const float* __restrict__ ws,
                                                    float* __restrict__ out) {
    const int mb   = blockIdx.x;
    const int b    = blockIdx.y;
    const int wv   = threadIdx.x >> 6;
    const int lane = threadIdx.x & 63;
    const int seg  = blockIdx.z * 4 + wv;          // 0..15

    __shared__ __align__(16) float best[4][256];

    const char* Wq = (const char*)W + (size_t)(mb * 256 + lane * 4) * 4;
    const int4*  off4 = (const int4*)(soff + b * PITCH);
    const float* xs   = sx + b * PITCH;
    const int k0 = seg * 64;
    const int base = k0 >> 2;

    // ---- exclusive prefix over segments (ascending s) ----
    float cw0 = 0, cw1 = 0, cw2 = 0, cw3 = 0;
    float ct0 = 0, ct1 = 0, ct2 = 0, ct3 = 0;
    const int pidx = (b * 4 + mb) * 16 * 256 + lane * 4;
    for (int s = 0; s < seg; ++s) {
        const float4 a = *(const float4*)&ws[SEGBASE + pidx + s * 256];
        const float4 t = *(const float4*)&ws[SEGBASE + SEGSZ + pidx + s * 256];
        cw0 = __fadd_rn(cw0, a.x); cw1 = __fadd_rn(cw1, a.y);
        cw2 = __fadd_rn(cw2, a.z); cw3 = __fadd_rn(cw3, a.w);
        ct0 = __fadd_rn(ct0, t.x); ct1 = __fadd_rn(ct1, t.y);
        ct2 = __fadd_rn(ct2, t.z); ct3 = __fadd_rn(ct3, t.w);
    }

    float bn0 = 0, bn1 = 0, bn2 = 0, bn3 = 0;
    float bd0 = -1.0f, bd1 = -1.0f, bd2 = -1.0f, bd3 = -1.0f;

#define GATE(cwv, ctv, bnv, bdv, wvv, xx, xxn)                                 \
    do {                                                                       \
        cwv = __fadd_rn(cwv, (wvv));                                           \
        ctv = __builtin_fmaf((wvv), (xx), ctv);                                \
        const float dn = __fadd_rn(cwv, -1.0f);                                \
        const bool v = (ctv >= __fmul_rn((xx), dn))                            \
                     & (ctv <= __fmul_rn((xxn), dn));                          \
        const bool u = v & (bdv < 0.0f);                                       \
        bnv = u ? ctv : bnv;                                                   \
        bdv = u ? dn  : bdv;                                                   \
    } while (0)

#define GATE4(wvv, xx, xxn)                                                    \
    do {                                                                       \
        GATE(cw0, ct0, bn0, bd0, (wvv).x, (xx), (xxn));                        \
        GATE(cw1, ct1, bn1, bd1, (wvv).y, (xx), (xxn));                        \
        GATE(cw2, ct2, bn2, bd2, (wvv).z, (xx), (xxn));                        \
        GATE(cw3, ct3, bn3, bd3, (wvv).w, (xx), (xxn));                        \
    } while (0)

    {
        float4 buf[4][4];
#pragma unroll
        for (int p = 0; p < 4; ++p) { const int4 o = off4[base + p]; LOADB(buf[p], o); }
        WALL();
#pragma unroll
        for (int it = 0; it < 16; ++it) {
            const int k = k0 + it * 4;
            const float xa = xs[k],     xb = xs[k + 1];
            const float xc = xs[k + 2], xd = xs[k + 3], xe = xs[k + 4];
            GATE4(buf[it & 3][0], xa, xb);
            GATE4(buf[it & 3][1], xb, xc);
            GATE4(buf[it & 3][2], xc, xd);
            GATE4(buf[it & 3][3], xd, xe);
            WALL();
            const int4 o = off4[base + it + 4];
            LOADB(buf[it & 3], o);
            WALL();
        }
        if (seg == 15) {
            // epilogue row 1024: buf[0] reloaded at it=12 from off4[256] (.x = off[1024])
            GATE4(buf[0][0], xs[1024], xs[1025]);           // xs[1025] = MAXT pad
        }
    }

    const float c0 = (bd0 > 0.0f) ? bn0 / bd0 : MAXT;       // exact IEEE div
    const float c1 = (bd1 > 0.0f) ? bn1 / bd1 : MAXT;
    const float c2 = (bd2 > 0.0f) ? bn2 / bd2 : MAXT;
    const float c3 = (bd3 > 0.0f) ? bn3 / bd3 : MAXT;
    *(float4*)&best[wv][lane * 4] = make_float4(c0, c1, c2, c3);
    __syncthreads();

    if (threadIdx.x < 256) {
        const int t = threadIdx.x;
        float r = fminf(fminf(best[0][t], best[1][t]), fminf(best[2][t], best[3][t]));
        atomicMin((unsigned*)(out + b * M_OUT + mb * 256 + t), __float_as_uint(r));
    }
}

extern "C" void kernel_launch(void* const* d_in, const int* in_sizes, int n_in,
                              void* d_out, int out_size, void* d_ws, size_t ws_size,
                              hipStream_t stream) {
    const float* X = (const float*)d_in[0];   // [64, 1024]
    const float* W = (const float*)d_in[1];   // [1025, 1024]
    float* out = (float*)d_out;               // [64, 1024]

    float* wsf  = (float*)d_ws;
    float* sx   = wsf;                                     // [64][PITCH]
    int*   soff = (int*)(wsf + BATCH * PITCH);             // [64][PITCH]

    dim3 g1(5, BATCH);
    rank_kernel<<<g1, 512, 0, stream>>>(X, sx, soff, out);

    dim3 gp(4, BATCH, 4);
    snn_pass1<<<gp, 256, 0, stream>>>(W, sx, soff, wsf);
    snn_pass2<<<gp, 256, 0, stream>>>(W, sx, soff, wsf, out);
}